// Round 9
// baseline (212.214 us; speedup 1.0000x reference)
//
#include <hip/hip_runtime.h>
#include <math.h>

#define B_ 8
#define C_ 128
#define N_ 16384
#define SCALE_ 0.17677669529663687f
#define EPS_ 1e-5f

#define KV_STRIDE 36    // k/v tiles [128][36] fp32 (ctx kernel)
#define XU_STRIDE 68    // packed f16-pair (uint) tile stride
#define REC_ 4224       // per-block record: 4096 P + 128 S

typedef _Float16 half8 __attribute__((ext_vector_type(8)));
typedef float floatx4 __attribute__((ext_vector_type(4)));

static __device__ inline unsigned short f16bits(float v) {
  _Float16 h = (_Float16)v;
  return __builtin_bit_cast(unsigned short, h);
}

// pack two floats into one hi-pair uint and one lo-pair uint (split-f16)
static __device__ inline void pack2(float a0, float a1,
                                    unsigned int& hp, unsigned int& lp) {
  _Float16 h0 = (_Float16)a0;
  _Float16 h1 = (_Float16)a1;
  float l0f = (a0 - (float)h0) * 2048.0f;
  float l1f = (a1 - (float)h1) * 2048.0f;
  hp = ((unsigned int)__builtin_bit_cast(unsigned short, h1) << 16) |
       (unsigned int)__builtin_bit_cast(unsigned short, h0);
  lp = ((unsigned int)f16bits(l1f) << 16) | (unsigned int)f16bits(l0f);
}

static __device__ inline void split8(const float* p, half8& hi, half8& lo) {
  float4 f0 = *(const float4*)p;
  float4 f1 = *(const float4*)(p + 4);
  float fv[8] = {f0.x, f0.y, f0.z, f0.w, f1.x, f1.y, f1.z, f1.w};
#pragma unroll
  for (int j = 0; j < 8; ++j) {
    _Float16 hj = (_Float16)fv[j];
    hi[j] = hj;
    lo[j] = (_Float16)((fv[j] - (float)hj) * 2048.0f);
  }
}

// ---------------------------------------------------------------------------
// Kernel 1 (UNCHANGED from round 8, proven): 16-wave blocks, each wave owns
// 16 k|v rows; P via per-wave MFMA tile-jobs. grid = B_*32, block = 1024.
// ---------------------------------------------------------------------------
__global__ __launch_bounds__(1024, 4) void lin_attn_ctx(
    const float* __restrict__ x, const float* __restrict__ wqkv,
    float* __restrict__ Ws)
{
  __shared__ __align__(16) unsigned int xhiu[32 * XU_STRIDE];
  __shared__ __align__(16) unsigned int xlou[32 * XU_STRIDE];
  __shared__ __align__(16) float ks[128 * KV_STRIDE];
  __shared__ __align__(16) float vs[128 * KV_STRIDE];

  const int t = threadIdx.x;
  const int bpb = gridDim.x / B_;        // 32
  const int b = blockIdx.x / bpb;
  const int blk = blockIdx.x - b * bpb;
  const int nchunks = 512 / bpb;         // 16
  const int pbase = blk * (nchunks << 5);

  const int lane = t & 63;
  const int wave = t >> 6;               // 0..15; waves 0-7: k, 8-15: v
  const int l15 = lane & 15;
  const int quad = lane >> 4;

  half8 ahi[4], alo[4];
#pragma unroll
  for (int s = 0; s < 4; ++s)
    split8(wqkv + (size_t)(128 + (wave << 4) + l15) * C_ + (s << 5) + (quad << 3),
           ahi[s], alo[s]);

  const int hj = wave >> 2;
  const int at = (wave >> 1) & 1;
  const int bt = wave & 1;
  floatx4 pacc1 = (floatx4){0.f, 0.f, 0.f, 0.f};
  floatx4 pacc2 = (floatx4){0.f, 0.f, 0.f, 0.f};
  float sacc[4] = {0.f, 0.f, 0.f, 0.f};

  const float* xb = x + ((size_t)b * C_) * N_;
  const int kp0 = t >> 4;            // 0..63
  const int pq0 = (t & 15) << 1;     // 0,2,..,30

  float2 fa0, fa1;
  {
    const float* p = xb + pbase + pq0;
    fa0 = *(const float2*)(p + (size_t)(2 * kp0) * N_);
    fa1 = *(const float2*)(p + (size_t)(2 * kp0 + 1) * N_);
  }

  for (int c4 = 0; c4 < nchunks; ++c4) {
    __syncthreads();   // A

    half8 eh, el, vh, vl;
    if (c4 > 0) {
      split8(&ks[((hj << 5) + (at << 4) + l15) * KV_STRIDE + (quad << 3)], eh, el);
      split8(&vs[((hj << 5) + (bt << 4) + l15) * KV_STRIDE + (quad << 3)], vh, vl);
    }

    {
      float a0[2] = {fa0.x, fa0.y};
      float a1[2] = {fa1.x, fa1.y};
#pragma unroll
      for (int j = 0; j < 2; ++j) {
        unsigned int hp, lp;
        pack2(a0[j], a1[j], hp, lp);
        xhiu[(pq0 + j) * XU_STRIDE + kp0] = hp;
        xlou[(pq0 + j) * XU_STRIDE + kp0] = lp;
      }
    }

    if (c4 > 0) {
      pacc1 = __builtin_amdgcn_mfma_f32_16x16x32_f16(eh, vh, pacc1, 0, 0, 0);
      pacc2 = __builtin_amdgcn_mfma_f32_16x16x32_f16(eh, vl, pacc2, 0, 0, 0);
      pacc2 = __builtin_amdgcn_mfma_f32_16x16x32_f16(el, vh, pacc2, 0, 0, 0);
    }

    __syncthreads();   // B

    if (c4 + 1 < nchunks) {
      const float* p = xb + pbase + ((c4 + 1) << 5) + pq0;
      fa0 = *(const float2*)(p + (size_t)(2 * kp0) * N_);
      fa1 = *(const float2*)(p + (size_t)(2 * kp0 + 1) * N_);
    }

    floatx4 acc1[2], acc2[2];
#pragma unroll
    for (int c = 0; c < 2; ++c) {
      acc1[c] = (floatx4){0.f, 0.f, 0.f, 0.f};
      acc2[c] = (floatx4){0.f, 0.f, 0.f, 0.f};
    }
    __builtin_amdgcn_s_setprio(1);
#pragma unroll
    for (int s = 0; s < 4; ++s) {
#pragma unroll
      for (int c = 0; c < 2; ++c) {
        int off = ((c << 4) + l15) * XU_STRIDE + (s << 4) + (quad << 2);
        half8 bh = __builtin_bit_cast(half8, *(const uint4*)&xhiu[off]);
        half8 bl = __builtin_bit_cast(half8, *(const uint4*)&xlou[off]);
        acc1[c] = __builtin_amdgcn_mfma_f32_16x16x32_f16(ahi[s], bh, acc1[c], 0, 0, 0);
        acc2[c] = __builtin_amdgcn_mfma_f32_16x16x32_f16(ahi[s], bl, acc2[c], 0, 0, 0);
        acc2[c] = __builtin_amdgcn_mfma_f32_16x16x32_f16(alo[s], bh, acc2[c], 0, 0, 0);
      }
    }
    __builtin_amdgcn_s_setprio(0);

    if (wave < 8) {
#pragma unroll
      for (int c = 0; c < 2; ++c) {
        int px = (c << 4) + l15;
#pragma unroll
        for (int reg = 0; reg < 4; ++reg) {
          float val = acc1[c][reg] + acc2[c][reg] * (1.0f / 2048.0f);
          int row = (wave << 4) + (quad << 2) + reg;
          float e = __expf(val);
          ks[row * KV_STRIDE + px] = e;
          sacc[reg] += e;
        }
      }
    } else {
#pragma unroll
      for (int c = 0; c < 2; ++c) {
        int px = (c << 4) + l15;
#pragma unroll
        for (int reg = 0; reg < 4; ++reg) {
          float val = acc1[c][reg] + acc2[c][reg] * (1.0f / 2048.0f);
          int row = ((wave - 8) << 4) + (quad << 2) + reg;
          vs[row * KV_STRIDE + px] = val;
        }
      }
    }
  }

  __syncthreads();
  {
    half8 eh, el, vh, vl;
    split8(&ks[((hj << 5) + (at << 4) + l15) * KV_STRIDE + (quad << 3)], eh, el);
    split8(&vs[((hj << 5) + (bt << 4) + l15) * KV_STRIDE + (quad << 3)], vh, vl);
    pacc1 = __builtin_amdgcn_mfma_f32_16x16x32_f16(eh, vh, pacc1, 0, 0, 0);
    pacc2 = __builtin_amdgcn_mfma_f32_16x16x32_f16(eh, vl, pacc2, 0, 0, 0);
    pacc2 = __builtin_amdgcn_mfma_f32_16x16x32_f16(el, vh, pacc2, 0, 0, 0);
  }

  {
    float* rec = Ws + (size_t)blockIdx.x * REC_;
#pragma unroll
    for (int reg = 0; reg < 4; ++reg) {
      int dk = (at << 4) + (quad << 2) + reg;
      int dv = (bt << 4) + l15;
      rec[(((hj << 5) + dk) << 5) + dv] =
          pacc1[reg] + pacc2[reg] * (1.0f / 2048.0f);
    }
    if (wave < 8) {
#pragma unroll
      for (int reg = 0; reg < 4; ++reg) {
        float s = sacc[reg];
        s += __shfl_xor(s, 1);
        s += __shfl_xor(s, 2);
        s += __shfl_xor(s, 4);
        s += __shfl_xor(s, 8);
        sacc[reg] = s;
      }
      if (l15 == 0) {
#pragma unroll
        for (int reg = 0; reg < 4; ++reg)
          rec[4096 + (wave << 4) + (quad << 2) + reg] = sacc[reg];
      }
    }
  }
}

// ---------------------------------------------------------------------------
// Fused reduce+gmat (UNCHANGED): grid = B_*32, block = 256
// ---------------------------------------------------------------------------
__global__ void lin_attn_redg(const float* __restrict__ Ws, int slots,
                              const float* __restrict__ wout,
                              float* __restrict__ G)
{
  __shared__ float p2[256];
  __shared__ float cx[128];
  __shared__ float ss[4];

  const int t = threadIdx.x;
  const int b = blockIdx.x >> 5;
  const int seg = blockIdx.x & 31;
  const int R0 = seg << 2;
  const int hs = slots >> 1;

  {
    const int e = t & 127;
    const int half = t >> 7;
    const float* src = Ws + ((size_t)b * slots + (size_t)half * hs) * REC_ +
                       R0 * 32 + e;
    float s = 0.f;
    for (int k = 0; k < hs; ++k) s += src[(size_t)k * REC_];
    p2[half * 128 + e] = s;
  }
  {
    const int row4 = t >> 6;
    const int lane = t & 63;
    float sv = (lane < slots)
             ? Ws[((size_t)b * slots + lane) * REC_ + 4096 + R0 + row4] : 0.f;
    sv += __shfl_xor(sv, 1);
    sv += __shfl_xor(sv, 2);
    sv += __shfl_xor(sv, 4);
    sv += __shfl_xor(sv, 8);
    sv += __shfl_xor(sv, 16);
    sv += __shfl_xor(sv, 32);
    if (lane == 0) ss[row4] = sv;
  }
  __syncthreads();
  if (t < 128) {
    cx[t] = (p2[t] + p2[128 + t]) / (ss[t >> 5] * 16384.f);
  }
  __syncthreads();
  {
    const int o = t >> 1;
    const int pr = t & 1;
#pragma unroll
    for (int p = 0; p < 2; ++p) {
      const int row4 = pr * 2 + p;
      const int grow = R0 + row4;
      const int h = grow >> 5;
      const float* wrow = wout + (size_t)o * 128 + h * 32;
      const float* crow = &cx[row4 * 32];
      float s = 0.f;
#pragma unroll
      for (int q = 0; q < 8; ++q) {
        float4 w4 = *(const float4*)&wrow[q * 4];
        float4 c4 = *(const float4*)&crow[q * 4];
        s += w4.x * c4.x + w4.y * c4.y + w4.z * c4.z + w4.w * c4.w;
      }
      G[(size_t)b * 16384 + (size_t)o * 128 + grow] = s * SCALE_;
    }
  }
}

// ---------------------------------------------------------------------------
// Kernel 2 (RESTRUCTURED, 16-wave producer-consumer): waves 0-7 = q-pipeline
// (16 w_q rows each), waves 8-15 = y-pipeline (16 G rows each), pipelined
// one chunk apart. Per-wave fragments 32 VGPR -> ~16 waves/CU.
// Softmax without max-sub (|q|~N(0,1), overflow-safe; ctx already does bare
// exp). LN partials double-buffered by chunk parity. 2 barriers/iter.
// grid = B_*32, block = 1024.
// ---------------------------------------------------------------------------
__global__ __launch_bounds__(1024, 4) void lin_attn_out(
    const float* __restrict__ x, const float* __restrict__ wqkv,
    const float* __restrict__ G, const float* __restrict__ bout,
    const float* __restrict__ alpha, const float* __restrict__ beta,
    float* __restrict__ out)
{
  __shared__ __align__(16) unsigned int xh[2][32 * XU_STRIDE];
  __shared__ __align__(16) unsigned int xl[2][32 * XU_STRIDE];
  __shared__ __align__(16) unsigned int qhiu[32 * XU_STRIDE];
  __shared__ __align__(16) unsigned int qlou[32 * XU_STRIDE];
  __shared__ float ssum[256];          // [qwave][px]
  __shared__ float red_s[2][256];      // [chunk parity][ywave*32+px]
  __shared__ float red_q[2][256];

  const int t = threadIdx.x;
  const int bpb = gridDim.x / B_;        // 32
  const int b = blockIdx.x / bpb;
  const int blk = blockIdx.x - b * bpb;
  const int nchunks = 512 / bpb;         // 16
  const int pbase = blk * (nchunks << 5);

  const int lane = t & 63;
  const int wave = t >> 6;               // 0..15
  const int l15 = lane & 15;
  const int quad = lane >> 4;
  const bool qw = (wave < 8);
  const int yw = wave - 8;               // y-wave index (valid when !qw)

  // persistent A fragments: q-waves take w_q rows, y-waves take G rows
  half8 ahi[4], alo[4];
  {
    const float* base = qw
        ? (wqkv + (size_t)((wave << 4) + l15) * C_)
        : (G + (size_t)b * 16384 + (size_t)((yw << 4) + l15) * 128);
#pragma unroll
    for (int s = 0; s < 4; ++s)
      split8(base + (s << 5) + (quad << 3), ahi[s], alo[s]);
  }

  // y-wave channel constants: ch = yw*16 + quad*4 + reg
  float bch[4], ach[4], bech[4];
  if (!qw) {
#pragma unroll
    for (int reg = 0; reg < 4; ++reg) {
      int ch = (yw << 4) + (quad << 2) + reg;
      bch[reg] = bout[ch];
      ach[reg] = alpha[ch];
      bech[reg] = beta[ch];
    }
  }

  const float* xb = x + ((size_t)b * C_) * N_;
  float* ob0 = out + ((size_t)b * C_) * N_ + pbase;
  const int kp0 = t >> 4;            // 0..63
  const int pq0 = (t & 15) << 1;     // 0,2,..,30

  // prologue: prefetch + stage chunk 0 into buffer 0
  float2 fa0, fa1;
  {
    const float* p = xb + pbase + pq0;
    fa0 = *(const float2*)(p + (size_t)(2 * kp0) * N_);
    fa1 = *(const float2*)(p + (size_t)(2 * kp0 + 1) * N_);
    float a0[2] = {fa0.x, fa0.y};
    float a1[2] = {fa1.x, fa1.y};
#pragma unroll
    for (int j = 0; j < 2; ++j) {
      unsigned int hp, lp;
      pack2(a0[j], a1[j], hp, lp);
      xh[0][(pq0 + j) * XU_STRIDE + kp0] = hp;
      xl[0][(pq0 + j) * XU_STRIDE + kp0] = lp;
    }
  }

  float eq[2][4];     // q-waves: unnormalized exp values (this chunk)
  float sown[2];      // q-waves: own 16-ch partial sum
  float yv[2][4];     // y-waves: y+bias of the chunk finished last iter

  for (int i = 0; i <= nchunks; ++i) {
    __syncthreads();   // A: stage(i) visible; qhat(i-1) visible; red(i-2) visible

    // prefetch chunk i+1 (all threads)
    if (i + 1 < nchunks) {
      const float* p = xb + pbase + ((i + 1) << 5) + pq0;
      fa0 = *(const float2*)(p + (size_t)(2 * kp0) * N_);
      fa1 = *(const float2*)(p + (size_t)(2 * kp0 + 1) * N_);
    }

    if (qw) {
      // ---- q GEMM chunk i + exp + wave-partial sums ----
      if (i < nchunks) {
        const int cur = i & 1;
        floatx4 a1c[2], a2c[2];
#pragma unroll
        for (int c = 0; c < 2; ++c) {
          a1c[c] = (floatx4){0.f, 0.f, 0.f, 0.f};
          a2c[c] = (floatx4){0.f, 0.f, 0.f, 0.f};
        }
        __builtin_amdgcn_s_setprio(1);
#pragma unroll
        for (int s = 0; s < 4; ++s) {
#pragma unroll
          for (int c = 0; c < 2; ++c) {
            int off = ((c << 4) + l15) * XU_STRIDE + (s << 4) + (quad << 2);
            half8 bh = __builtin_bit_cast(half8, *(const uint4*)&xh[cur][off]);
            half8 bl = __builtin_bit_cast(half8, *(const uint4*)&xl[cur][off]);
            a1c[c] = __builtin_amdgcn_mfma_f32_16x16x32_f16(ahi[s], bh, a1c[c], 0, 0, 0);
            a2c[c] = __builtin_amdgcn_mfma_f32_16x16x32_f16(ahi[s], bl, a2c[c], 0, 0, 0);
            a2c[c] = __builtin_amdgcn_mfma_f32_16x16x32_f16(alo[s], bh, a2c[c], 0, 0, 0);
          }
        }
        __builtin_amdgcn_s_setprio(0);
#pragma unroll
        for (int c = 0; c < 2; ++c) {
          float s4 = 0.f;
#pragma unroll
          for (int reg = 0; reg < 4; ++reg) {
            float v = a1c[c][reg] + a2c[c][reg] * (1.0f / 2048.0f);
            float e = __expf(v);    // no max-sub: |q|~N(0,1), safe
            eq[c][reg] = e;
            s4 += e;
          }
          s4 += __shfl_xor(s4, 16);
          s4 += __shfl_xor(s4, 32);
          sown[c] = s4;
          if (quad == 0) ssum[(wave << 5) + (c << 4) + l15] = s4;
        }
      }
    } else {
      // ---- deferred LN-final + store for chunk i-2 ----
      if (i >= 2) {
        const float* rs = red_s[i & 1];     // (i-2)&1 == i&1
        const float* rq = red_q[i & 1];
        float* ob = ob0 + ((i - 2) << 5);
#pragma unroll
        for (int c = 0; c < 2; ++c) {
          int px = (c << 4) + l15;
          float ts = ((rs[px] + rs[32 + px]) + (rs[64 + px] + rs[96 + px])) +
                     ((rs[128 + px] + rs[160 + px]) + (rs[192 + px] + rs[224 + px]));
          float tq = ((rq[px] + rq[32 + px]) + (rq[64 + px] + rq[96 + px])) +
                     ((rq[128 + px] + rq[160 + px]) + (rq[192 + px] + rq[224 + px]));
          float mean = ts * (1.f / 128.f);
          float var = tq * (1.f / 128.f) - mean * mean;
          float rstd = 1.f / sqrtf(var + EPS_);
#pragma unroll
          for (int reg = 0; reg < 4; ++reg) {
            int ch = (yw << 4) + (quad << 2) + reg;
            ob[(size_t)ch * N_ + px] =
                (yv[c][reg] - mean) * rstd * ach[reg] + bech[reg];
          }
        }
      }
      // ---- y GEMM chunk i-1 from qhat; y+bias -> yv; LN partials ----
      if (i >= 1) {
        floatx4 a1c[2], a2c[2];
#pragma unroll
        for (int c = 0; c < 2; ++c) {
          a1c[c] = (floatx4){0.f, 0.f, 0.f, 0.f};
          a2c[c] = (floatx4){0.f, 0.f, 0.f, 0.f};
        }
        __builtin_amdgcn_s_setprio(1);
#pragma unroll
        for (int s = 0; s < 4; ++s) {
#pragma unroll
          for (int c = 0; c < 2; ++c) {
            int off = ((c << 4) + l15) * XU_STRIDE + (s << 4) + (quad << 2);
            half8 bh = __builtin_bit_cast(half8, *(const uint4*)&qhiu[off]);
            half8 bl = __builtin_bit_cast(half8, *(const uint4*)&qlou[off]);
            a1c[c] = __builtin_amdgcn_mfma_f32_16x16x32_f16(ahi[s], bh, a1c[c], 0, 0, 0);
            a2c[c] = __builtin_amdgcn_mfma_f32_16x16x32_f16(ahi[s], bl, a2c[c], 0, 0, 0);
            a2c[c] = __builtin_amdgcn_mfma_f32_16x16x32_f16(alo[s], bh, a2c[c], 0, 0, 0);
          }
        }
        __builtin_amdgcn_s_setprio(0);
        const int cb = (i - 1) & 1;
#pragma unroll
        for (int c = 0; c < 2; ++c) {
          float sm = 0.f, sq = 0.f;
#pragma unroll
          for (int reg = 0; reg < 4; ++reg) {
            float v = a1c[c][reg] + a2c[c][reg] * (1.0f / 2048.0f) + bch[reg];
            yv[c][reg] = v;
            sm += v;
            sq += v * v;
          }
          sm += __shfl_xor(sm, 16);  sq += __shfl_xor(sq, 16);
          sm += __shfl_xor(sm, 32);  sq += __shfl_xor(sq, 32);
          if (quad == 0) {
            red_s[cb][(yw << 5) + (c << 4) + l15] = sm;
            red_q[cb][(yw << 5) + (c << 4) + l15] = sq;
          }
        }
      }
    }

    // ---- stage chunk i+1 into xh[(i+1)&1] (all waves) ----
    if (i + 1 < nchunks) {
      const int nx = (i + 1) & 1;
      float a0[2] = {fa0.x, fa0.y};
      float a1[2] = {fa1.x, fa1.y};
#pragma unroll
      for (int j = 0; j < 2; ++j) {
        unsigned int hp, lp;
        pack2(a0[j], a1[j], hp, lp);
        xh[nx][(pq0 + j) * XU_STRIDE + kp0] = hp;
        xl[nx][(pq0 + j) * XU_STRIDE + kp0] = lp;
      }
    }

    __syncthreads();   // B: ssum visible; y GEMM qhat reads done

    // ---- q-waves: normalize with head-pair sum, emit qhat(i) ----
    if (qw && i < nchunks) {
#pragma unroll
      for (int c = 0; c < 2; ++c) {
        int px = (c << 4) + l15;
        float pairs = ssum[((wave ^ 1) << 5) + (c << 4) + l15];
        float inv = 1.0f / (sown[c] + pairs);   // scale folded into G
        unsigned int h0, l0, h1, l1;
        pack2(eq[c][0] * inv, eq[c][1] * inv, h0, l0);
        pack2(eq[c][2] * inv, eq[c][3] * inv, h1, l1);
        int kp = (wave << 3) + (quad << 1);
        uint2 hu; hu.x = h0; hu.y = h1;
        uint2 lu; lu.x = l0; lu.y = l1;
        *(uint2*)&qhiu[px * XU_STRIDE + kp] = hu;
        *(uint2*)&qlou[px * XU_STRIDE + kp] = lu;
      }
    }
  }

  // ---- epilogue: LN-final + store for chunk nchunks-1 ----
  __syncthreads();
  if (!qw) {
    const float* rs = red_s[(nchunks - 1) & 1];
    const float* rq = red_q[(nchunks - 1) & 1];
    float* ob = ob0 + ((nchunks - 1) << 5);
#pragma unroll
    for (int c = 0; c < 2; ++c) {
      int px = (c << 4) + l15;
      float ts = ((rs[px] + rs[32 + px]) + (rs[64 + px] + rs[96 + px])) +
                 ((rs[128 + px] + rs[160 + px]) + (rs[192 + px] + rs[224 + px]));
      float tq = ((rq[px] + rq[32 + px]) + (rq[64 + px] + rq[96 + px])) +
                 ((rq[128 + px] + rq[160 + px]) + (rq[192 + px] + rq[224 + px]));
      float mean = ts * (1.f / 128.f);
      float var = tq * (1.f / 128.f) - mean * mean;
      float rstd = 1.f / sqrtf(var + EPS_);
#pragma unroll
      for (int reg = 0; reg < 4; ++reg) {
        int ch = (yw << 4) + (quad << 2) + reg;
        ob[(size_t)ch * N_ + px] =
            (yv[c][reg] - mean) * rstd * ach[reg] + bech[reg];
      }
    }
  }
}

extern "C" void kernel_launch(void* const* d_in, const int* in_sizes, int n_in,
                              void* d_out, int out_size, void* d_ws, size_t ws_size,
                              hipStream_t stream) {
  const float* x     = (const float*)d_in[0];
  const float* wqkv  = (const float*)d_in[1];
  const float* wout  = (const float*)d_in[2];
  const float* bout  = (const float*)d_in[3];
  const float* alpha = (const float*)d_in[4];
  const float* beta  = (const float*)d_in[5];
  float* outp = (float*)d_out;

  // workspace layout: G | (reserved) | records
  float* G  = (float*)d_ws;                          // [B][128][128]
  float* Ws = G + (size_t)B_ * 16384 + B_ * 4096 + B_ * 128;

  const int bpb_ctx = 32;   // 256 blocks of 1024 threads = 1 block/CU

  lin_attn_ctx<<<dim3(B_ * bpb_ctx), dim3(1024), 0, stream>>>(x, wqkv, Ws);
  lin_attn_redg<<<dim3(B_ * 32), dim3(256), 0, stream>>>(Ws, bpb_ctx, wout, G);
  lin_attn_out<<<dim3(B_ * 32), dim3(1024), 0, stream>>>(x, wqkv, G, bout,
                                                         alpha, beta, outp);
}

// Round 10
// 199.859 us; speedup vs baseline: 1.0618x; 1.0618x over previous
//
#include <hip/hip_runtime.h>
#include <math.h>

#define B_ 8
#define C_ 128
#define N_ 16384
#define SCALE_ 0.17677669529663687f
#define EPS_ 1e-5f

#define KV_STRIDE 36    // k/v tiles [128][36] fp32 (ctx kernel)
#define XU_STRIDE 68    // packed f16-pair (uint) tile stride
#define REC_ 4224       // per-block record: 4096 P + 128 S

typedef _Float16 half8 __attribute__((ext_vector_type(8)));
typedef float floatx4 __attribute__((ext_vector_type(4)));

static __device__ inline unsigned short f16bits(float v) {
  _Float16 h = (_Float16)v;
  return __builtin_bit_cast(unsigned short, h);
}

// pack two floats into one hi-pair uint and one lo-pair uint (split-f16)
static __device__ inline void pack2(float a0, float a1,
                                    unsigned int& hp, unsigned int& lp) {
  _Float16 h0 = (_Float16)a0;
  _Float16 h1 = (_Float16)a1;
  float l0f = (a0 - (float)h0) * 2048.0f;
  float l1f = (a1 - (float)h1) * 2048.0f;
  hp = ((unsigned int)__builtin_bit_cast(unsigned short, h1) << 16) |
       (unsigned int)__builtin_bit_cast(unsigned short, h0);
  lp = ((unsigned int)f16bits(l1f) << 16) | (unsigned int)f16bits(l0f);
}

static __device__ inline void split8(const float* p, half8& hi, half8& lo) {
  float4 f0 = *(const float4*)p;
  float4 f1 = *(const float4*)(p + 4);
  float fv[8] = {f0.x, f0.y, f0.z, f0.w, f1.x, f1.y, f1.z, f1.w};
#pragma unroll
  for (int j = 0; j < 8; ++j) {
    _Float16 hj = (_Float16)fv[j];
    hi[j] = hj;
    lo[j] = (_Float16)((fv[j] - (float)hj) * 2048.0f);
  }
}

// ---------------------------------------------------------------------------
// Kernel 1 (UNCHANGED from round 8, proven): 16-wave blocks, each wave owns
// 16 k|v rows; P via per-wave MFMA tile-jobs. grid = B_*32, block = 1024.
// ---------------------------------------------------------------------------
__global__ __launch_bounds__(1024, 4) void lin_attn_ctx(
    const float* __restrict__ x, const float* __restrict__ wqkv,
    float* __restrict__ Ws)
{
  __shared__ __align__(16) unsigned int xhiu[32 * XU_STRIDE];
  __shared__ __align__(16) unsigned int xlou[32 * XU_STRIDE];
  __shared__ __align__(16) float ks[128 * KV_STRIDE];
  __shared__ __align__(16) float vs[128 * KV_STRIDE];

  const int t = threadIdx.x;
  const int bpb = gridDim.x / B_;        // 32
  const int b = blockIdx.x / bpb;
  const int blk = blockIdx.x - b * bpb;
  const int nchunks = 512 / bpb;         // 16
  const int pbase = blk * (nchunks << 5);

  const int lane = t & 63;
  const int wave = t >> 6;               // 0..15; waves 0-7: k, 8-15: v
  const int l15 = lane & 15;
  const int quad = lane >> 4;

  half8 ahi[4], alo[4];
#pragma unroll
  for (int s = 0; s < 4; ++s)
    split8(wqkv + (size_t)(128 + (wave << 4) + l15) * C_ + (s << 5) + (quad << 3),
           ahi[s], alo[s]);

  const int hj = wave >> 2;
  const int at = (wave >> 1) & 1;
  const int bt = wave & 1;
  floatx4 pacc1 = (floatx4){0.f, 0.f, 0.f, 0.f};
  floatx4 pacc2 = (floatx4){0.f, 0.f, 0.f, 0.f};
  float sacc[4] = {0.f, 0.f, 0.f, 0.f};

  const float* xb = x + ((size_t)b * C_) * N_;
  const int kp0 = t >> 4;            // 0..63
  const int pq0 = (t & 15) << 1;     // 0,2,..,30

  float2 fa0, fa1;
  {
    const float* p = xb + pbase + pq0;
    fa0 = *(const float2*)(p + (size_t)(2 * kp0) * N_);
    fa1 = *(const float2*)(p + (size_t)(2 * kp0 + 1) * N_);
  }

  for (int c4 = 0; c4 < nchunks; ++c4) {
    __syncthreads();   // A

    half8 eh, el, vh, vl;
    if (c4 > 0) {
      split8(&ks[((hj << 5) + (at << 4) + l15) * KV_STRIDE + (quad << 3)], eh, el);
      split8(&vs[((hj << 5) + (bt << 4) + l15) * KV_STRIDE + (quad << 3)], vh, vl);
    }

    {
      float a0[2] = {fa0.x, fa0.y};
      float a1[2] = {fa1.x, fa1.y};
#pragma unroll
      for (int j = 0; j < 2; ++j) {
        unsigned int hp, lp;
        pack2(a0[j], a1[j], hp, lp);
        xhiu[(pq0 + j) * XU_STRIDE + kp0] = hp;
        xlou[(pq0 + j) * XU_STRIDE + kp0] = lp;
      }
    }

    if (c4 > 0) {
      pacc1 = __builtin_amdgcn_mfma_f32_16x16x32_f16(eh, vh, pacc1, 0, 0, 0);
      pacc2 = __builtin_amdgcn_mfma_f32_16x16x32_f16(eh, vl, pacc2, 0, 0, 0);
      pacc2 = __builtin_amdgcn_mfma_f32_16x16x32_f16(el, vh, pacc2, 0, 0, 0);
    }

    __syncthreads();   // B

    if (c4 + 1 < nchunks) {
      const float* p = xb + pbase + ((c4 + 1) << 5) + pq0;
      fa0 = *(const float2*)(p + (size_t)(2 * kp0) * N_);
      fa1 = *(const float2*)(p + (size_t)(2 * kp0 + 1) * N_);
    }

    floatx4 acc1[2], acc2[2];
#pragma unroll
    for (int c = 0; c < 2; ++c) {
      acc1[c] = (floatx4){0.f, 0.f, 0.f, 0.f};
      acc2[c] = (floatx4){0.f, 0.f, 0.f, 0.f};
    }
    __builtin_amdgcn_s_setprio(1);
#pragma unroll
    for (int s = 0; s < 4; ++s) {
#pragma unroll
      for (int c = 0; c < 2; ++c) {
        int off = ((c << 4) + l15) * XU_STRIDE + (s << 4) + (quad << 2);
        half8 bh = __builtin_bit_cast(half8, *(const uint4*)&xhiu[off]);
        half8 bl = __builtin_bit_cast(half8, *(const uint4*)&xlou[off]);
        acc1[c] = __builtin_amdgcn_mfma_f32_16x16x32_f16(ahi[s], bh, acc1[c], 0, 0, 0);
        acc2[c] = __builtin_amdgcn_mfma_f32_16x16x32_f16(ahi[s], bl, acc2[c], 0, 0, 0);
        acc2[c] = __builtin_amdgcn_mfma_f32_16x16x32_f16(alo[s], bh, acc2[c], 0, 0, 0);
      }
    }
    __builtin_amdgcn_s_setprio(0);

    if (wave < 8) {
#pragma unroll
      for (int c = 0; c < 2; ++c) {
        int px = (c << 4) + l15;
#pragma unroll
        for (int reg = 0; reg < 4; ++reg) {
          float val = acc1[c][reg] + acc2[c][reg] * (1.0f / 2048.0f);
          int row = (wave << 4) + (quad << 2) + reg;
          float e = __expf(val);
          ks[row * KV_STRIDE + px] = e;
          sacc[reg] += e;
        }
      }
    } else {
#pragma unroll
      for (int c = 0; c < 2; ++c) {
        int px = (c << 4) + l15;
#pragma unroll
        for (int reg = 0; reg < 4; ++reg) {
          float val = acc1[c][reg] + acc2[c][reg] * (1.0f / 2048.0f);
          int row = ((wave - 8) << 4) + (quad << 2) + reg;
          vs[row * KV_STRIDE + px] = val;
        }
      }
    }
  }

  __syncthreads();
  {
    half8 eh, el, vh, vl;
    split8(&ks[((hj << 5) + (at << 4) + l15) * KV_STRIDE + (quad << 3)], eh, el);
    split8(&vs[((hj << 5) + (bt << 4) + l15) * KV_STRIDE + (quad << 3)], vh, vl);
    pacc1 = __builtin_amdgcn_mfma_f32_16x16x32_f16(eh, vh, pacc1, 0, 0, 0);
    pacc2 = __builtin_amdgcn_mfma_f32_16x16x32_f16(eh, vl, pacc2, 0, 0, 0);
    pacc2 = __builtin_amdgcn_mfma_f32_16x16x32_f16(el, vh, pacc2, 0, 0, 0);
  }

  {
    float* rec = Ws + (size_t)blockIdx.x * REC_;
#pragma unroll
    for (int reg = 0; reg < 4; ++reg) {
      int dk = (at << 4) + (quad << 2) + reg;
      int dv = (bt << 4) + l15;
      rec[(((hj << 5) + dk) << 5) + dv] =
          pacc1[reg] + pacc2[reg] * (1.0f / 2048.0f);
    }
    if (wave < 8) {
#pragma unroll
      for (int reg = 0; reg < 4; ++reg) {
        float s = sacc[reg];
        s += __shfl_xor(s, 1);
        s += __shfl_xor(s, 2);
        s += __shfl_xor(s, 4);
        s += __shfl_xor(s, 8);
        sacc[reg] = s;
      }
      if (l15 == 0) {
#pragma unroll
        for (int reg = 0; reg < 4; ++reg)
          rec[4096 + (wave << 4) + (quad << 2) + reg] = sacc[reg];
      }
    }
  }
}

// ---------------------------------------------------------------------------
// Fused reduce+gmat (UNCHANGED): grid = B_*32, block = 256
// ---------------------------------------------------------------------------
__global__ void lin_attn_redg(const float* __restrict__ Ws, int slots,
                              const float* __restrict__ wout,
                              float* __restrict__ G)
{
  __shared__ float p2[256];
  __shared__ float cx[128];
  __shared__ float ss[4];

  const int t = threadIdx.x;
  const int b = blockIdx.x >> 5;
  const int seg = blockIdx.x & 31;
  const int R0 = seg << 2;
  const int hs = slots >> 1;

  {
    const int e = t & 127;
    const int half = t >> 7;
    const float* src = Ws + ((size_t)b * slots + (size_t)half * hs) * REC_ +
                       R0 * 32 + e;
    float s = 0.f;
    for (int k = 0; k < hs; ++k) s += src[(size_t)k * REC_];
    p2[half * 128 + e] = s;
  }
  {
    const int row4 = t >> 6;
    const int lane = t & 63;
    float sv = (lane < slots)
             ? Ws[((size_t)b * slots + lane) * REC_ + 4096 + R0 + row4] : 0.f;
    sv += __shfl_xor(sv, 1);
    sv += __shfl_xor(sv, 2);
    sv += __shfl_xor(sv, 4);
    sv += __shfl_xor(sv, 8);
    sv += __shfl_xor(sv, 16);
    sv += __shfl_xor(sv, 32);
    if (lane == 0) ss[row4] = sv;
  }
  __syncthreads();
  if (t < 128) {
    cx[t] = (p2[t] + p2[128 + t]) / (ss[t >> 5] * 16384.f);
  }
  __syncthreads();
  {
    const int o = t >> 1;
    const int pr = t & 1;
#pragma unroll
    for (int p = 0; p < 2; ++p) {
      const int row4 = pr * 2 + p;
      const int grow = R0 + row4;
      const int h = grow >> 5;
      const float* wrow = wout + (size_t)o * 128 + h * 32;
      const float* crow = &cx[row4 * 32];
      float s = 0.f;
#pragma unroll
      for (int q = 0; q < 8; ++q) {
        float4 w4 = *(const float4*)&wrow[q * 4];
        float4 c4 = *(const float4*)&crow[q * 4];
        s += w4.x * c4.x + w4.y * c4.y + w4.z * c4.z + w4.w * c4.w;
      }
      G[(size_t)b * 16384 + (size_t)o * 128 + grow] = s * SCALE_;
    }
  }
}

// ---------------------------------------------------------------------------
// Kernel 2 (16-wave, 3-stage pipeline, ONE barrier/iter): q-waves 0-7
// (16 w_q rows each), y-waves 8-15 (16 G rows each). iter i:
//   q: normalize+emit(i-1) [ssum(i-1) visible] ; qGEMM(i)+exp+ssum(i)
//   y: LNfinal(i-3) ; yGEMM(i-2)+LNpartial(i-2) ; stage(i+1) [float4]
// All LDS buffers parity-double-buffered; each writer/reader same-parity
// pair is separated by >=1 top barrier. 19 iters, 19 barriers.
// grid = B_*32, block = 1024.
// ---------------------------------------------------------------------------
__global__ __launch_bounds__(1024, 4) void lin_attn_out(
    const float* __restrict__ x, const float* __restrict__ wqkv,
    const float* __restrict__ G, const float* __restrict__ bout,
    const float* __restrict__ alpha, const float* __restrict__ beta,
    float* __restrict__ out)
{
  __shared__ __align__(16) unsigned int xh[2][32 * XU_STRIDE];
  __shared__ __align__(16) unsigned int xl[2][32 * XU_STRIDE];
  __shared__ __align__(16) unsigned int qh[2][32 * XU_STRIDE];
  __shared__ __align__(16) unsigned int ql[2][32 * XU_STRIDE];
  __shared__ float ssum[2][256];       // [parity][qwave*32 + c*16 + l15]
  __shared__ float red_s[2][256];      // [parity][ywave*32 + c*16 + l15]
  __shared__ float red_q[2][256];

  const int t = threadIdx.x;
  const int bpb = gridDim.x / B_;        // 32
  const int b = blockIdx.x / bpb;
  const int blk = blockIdx.x - b * bpb;
  const int nchunks = 512 / bpb;         // 16
  const int pbase = blk * (nchunks << 5);

  const int lane = t & 63;
  const int wave = t >> 6;               // 0..15
  const int l15 = lane & 15;
  const int quad = lane >> 4;
  const bool qw = (wave < 8);
  const int yw = wave - 8;

  // persistent A fragments: q-waves w_q rows 16w..16w+15; y-waves G rows
  half8 ahi[4], alo[4];
  {
    const float* base = qw
        ? (wqkv + (size_t)((wave << 4) + l15) * C_)
        : (G + (size_t)b * 16384 + (size_t)((yw << 4) + l15) * 128);
#pragma unroll
    for (int s = 0; s < 4; ++s)
      split8(base + (s << 5) + (quad << 3), ahi[s], alo[s]);
  }

  float bch[4], ach[4], bech[4];
  if (!qw) {
#pragma unroll
    for (int reg = 0; reg < 4; ++reg) {
      int ch = (yw << 4) + (quad << 2) + reg;
      bch[reg] = bout[ch];
      ach[reg] = alpha[ch];
      bech[reg] = beta[ch];
    }
  }

  const float* xb = x + ((size_t)b * C_) * N_;
  float* ob0 = out + ((size_t)b * C_) * N_ + pbase;

  // staging by t>=512 (y-side), float4 mapping: 512 threads x 4 pair-writes
  const int st = t - 512;
  const int kp0 = st >> 3;             // 0..63 (valid for t>=512)
  const int pq0 = (st & 7) << 2;       // 0,4,..,28

  float4 fa0, fa1;
  if (t >= 512) {
    const float* p = xb + pbase + pq0;
    fa0 = *(const float4*)(p + (size_t)(2 * kp0) * N_);
    fa1 = *(const float4*)(p + (size_t)(2 * kp0 + 1) * N_);
    float a0[4] = {fa0.x, fa0.y, fa0.z, fa0.w};
    float a1[4] = {fa1.x, fa1.y, fa1.z, fa1.w};
#pragma unroll
    for (int j = 0; j < 4; ++j) {
      unsigned int hp, lp;
      pack2(a0[j], a1[j], hp, lp);
      xh[0][(pq0 + j) * XU_STRIDE + kp0] = hp;
      xl[0][(pq0 + j) * XU_STRIDE + kp0] = lp;
    }
  }

  float eq[2][4];   // q: unnormalized exp values of chunk i (held to i+1)
  float sown[2];    // q: own 16-row partial sums of chunk i
  float yv[2][4];   // y: y+bias of chunk i-2 (held to LNfinal at i+1)

  for (int i = 0; i <= nchunks + 2; ++i) {
    __syncthreads();   // the ONE barrier: publishes stage(i), qhat(i-1),
                       // ssum(i-1), red(i-2... per parity table)

    // prefetch chunk i+1 (staging threads)
    if (t >= 512 && i + 1 < nchunks) {
      const float* p = xb + pbase + ((i + 1) << 5) + pq0;
      fa0 = *(const float4*)(p + (size_t)(2 * kp0) * N_);
      fa1 = *(const float4*)(p + (size_t)(2 * kp0 + 1) * N_);
    }

    if (qw) {
      // ---- normalize + emit chunk i-1 (reads ssum(i-1), own eq/sown) ----
      if (i >= 1 && i - 1 < nchunks) {
        const int pe = (i - 1) & 1;
#pragma unroll
        for (int c = 0; c < 2; ++c) {
          int px = (c << 4) + l15;
          float pairs = ssum[pe][((wave ^ 1) << 5) + (c << 4) + l15];
          float inv = 1.0f / (sown[c] + pairs);   // scale folded into G
          unsigned int h0, l0, h1, l1;
          pack2(eq[c][0] * inv, eq[c][1] * inv, h0, l0);
          pack2(eq[c][2] * inv, eq[c][3] * inv, h1, l1);
          int kp = (wave << 3) + (quad << 1);
          uint2 hu; hu.x = h0; hu.y = h1;
          uint2 lu; lu.x = l0; lu.y = l1;
          *(uint2*)&qh[pe][px * XU_STRIDE + kp] = hu;
          *(uint2*)&ql[pe][px * XU_STRIDE + kp] = lu;
        }
      }
      // ---- q GEMM chunk i + exp + partial sums ----
      if (i < nchunks) {
        const int cur = i & 1;
        floatx4 a1c[2], a2c[2];
#pragma unroll
        for (int c = 0; c < 2; ++c) {
          a1c[c] = (floatx4){0.f, 0.f, 0.f, 0.f};
          a2c[c] = (floatx4){0.f, 0.f, 0.f, 0.f};
        }
        __builtin_amdgcn_s_setprio(1);
#pragma unroll
        for (int s = 0; s < 4; ++s) {
#pragma unroll
          for (int c = 0; c < 2; ++c) {
            int off = ((c << 4) + l15) * XU_STRIDE + (s << 4) + (quad << 2);
            half8 bh = __builtin_bit_cast(half8, *(const uint4*)&xh[cur][off]);
            half8 bl = __builtin_bit_cast(half8, *(const uint4*)&xl[cur][off]);
            a1c[c] = __builtin_amdgcn_mfma_f32_16x16x32_f16(ahi[s], bh, a1c[c], 0, 0, 0);
            a2c[c] = __builtin_amdgcn_mfma_f32_16x16x32_f16(ahi[s], bl, a2c[c], 0, 0, 0);
            a2c[c] = __builtin_amdgcn_mfma_f32_16x16x32_f16(alo[s], bh, a2c[c], 0, 0, 0);
          }
        }
        __builtin_amdgcn_s_setprio(0);
#pragma unroll
        for (int c = 0; c < 2; ++c) {
          float s4 = 0.f;
#pragma unroll
          for (int reg = 0; reg < 4; ++reg) {
            float v = a1c[c][reg] + a2c[c][reg] * (1.0f / 2048.0f);
            float e = __expf(v);    // no max-sub: |q|~N(0,1), safe
            eq[c][reg] = e;
            s4 += e;
          }
          s4 += __shfl_xor(s4, 16);
          s4 += __shfl_xor(s4, 32);
          sown[c] = s4;
          if (quad == 0) ssum[i & 1][(wave << 5) + (c << 4) + l15] = s4;
        }
      }
    } else {
      // ---- deferred LN-final + store for chunk i-3 (yv from iter i-1) ----
      if (i >= 3) {
        const int pf = (i - 3) & 1;
        const float* rs = red_s[pf];
        const float* rq = red_q[pf];
        float* ob = ob0 + ((i - 3) << 5);
#pragma unroll
        for (int c = 0; c < 2; ++c) {
          int px = (c << 4) + l15;
          float ts = ((rs[px] + rs[32 + px]) + (rs[64 + px] + rs[96 + px])) +
                     ((rs[128 + px] + rs[160 + px]) + (rs[192 + px] + rs[224 + px]));
          float tq = ((rq[px] + rq[32 + px]) + (rq[64 + px] + rq[96 + px])) +
                     ((rq[128 + px] + rq[160 + px]) + (rq[192 + px] + rq[224 + px]));
          float mean = ts * (1.f / 128.f);
          float var = tq * (1.f / 128.f) - mean * mean;
          float rstd = 1.f / sqrtf(var + EPS_);
#pragma unroll
          for (int reg = 0; reg < 4; ++reg) {
            int ch = (yw << 4) + (quad << 2) + reg;
            ob[(size_t)ch * N_ + px] =
                (yv[c][reg] - mean) * rstd * ach[reg] + bech[reg];
          }
        }
      }
      // ---- y GEMM chunk i-2 from qhat(i-2); LN partials ----
      if (i >= 2 && i - 2 < nchunks) {
        const int pe = i & 1;   // (i-2)&1
        floatx4 a1c[2], a2c[2];
#pragma unroll
        for (int c = 0; c < 2; ++c) {
          a1c[c] = (floatx4){0.f, 0.f, 0.f, 0.f};
          a2c[c] = (floatx4){0.f, 0.f, 0.f, 0.f};
        }
        __builtin_amdgcn_s_setprio(1);
#pragma unroll
        for (int s = 0; s < 4; ++s) {
#pragma unroll
          for (int c = 0; c < 2; ++c) {
            int off = ((c << 4) + l15) * XU_STRIDE + (s << 4) + (quad << 2);
            half8 bh = __builtin_bit_cast(half8, *(const uint4*)&qh[pe][off]);
            half8 bl = __builtin_bit_cast(half8, *(const uint4*)&ql[pe][off]);
            a1c[c] = __builtin_amdgcn_mfma_f32_16x16x32_f16(ahi[s], bh, a1c[c], 0, 0, 0);
            a2c[c] = __builtin_amdgcn_mfma_f32_16x16x32_f16(ahi[s], bl, a2c[c], 0, 0, 0);
            a2c[c] = __builtin_amdgcn_mfma_f32_16x16x32_f16(alo[s], bh, a2c[c], 0, 0, 0);
          }
        }
        __builtin_amdgcn_s_setprio(0);
#pragma unroll
        for (int c = 0; c < 2; ++c) {
          float sm = 0.f, sq = 0.f;
#pragma unroll
          for (int reg = 0; reg < 4; ++reg) {
            float v = a1c[c][reg] + a2c[c][reg] * (1.0f / 2048.0f) + bch[reg];
            yv[c][reg] = v;
            sm += v;
            sq += v * v;
          }
          sm += __shfl_xor(sm, 16);  sq += __shfl_xor(sq, 16);
          sm += __shfl_xor(sm, 32);  sq += __shfl_xor(sq, 32);
          if (quad == 0) {
            red_s[pe][(yw << 5) + (c << 4) + l15] = sm;
            red_q[pe][(yw << 5) + (c << 4) + l15] = sq;
          }
        }
      }
    }

    // ---- stage chunk i+1 into xh[(i+1)&1] (staging threads) ----
    if (t >= 512 && i + 1 < nchunks) {
      const int nx = (i + 1) & 1;
      float a0[4] = {fa0.x, fa0.y, fa0.z, fa0.w};
      float a1[4] = {fa1.x, fa1.y, fa1.z, fa1.w};
#pragma unroll
      for (int j = 0; j < 4; ++j) {
        unsigned int hp, lp;
        pack2(a0[j], a1[j], hp, lp);
        xh[nx][(pq0 + j) * XU_STRIDE + kp0] = hp;
        xl[nx][(pq0 + j) * XU_STRIDE + kp0] = lp;
      }
    }
  }
}

extern "C" void kernel_launch(void* const* d_in, const int* in_sizes, int n_in,
                              void* d_out, int out_size, void* d_ws, size_t ws_size,
                              hipStream_t stream) {
  const float* x     = (const float*)d_in[0];
  const float* wqkv  = (const float*)d_in[1];
  const float* wout  = (const float*)d_in[2];
  const float* bout  = (const float*)d_in[3];
  const float* alpha = (const float*)d_in[4];
  const float* beta  = (const float*)d_in[5];
  float* outp = (float*)d_out;

  // workspace layout: G | (reserved) | records
  float* G  = (float*)d_ws;                          // [B][128][128]
  float* Ws = G + (size_t)B_ * 16384 + B_ * 4096 + B_ * 128;

  const int bpb_ctx = 32;   // 256 blocks of 1024 threads = 1 block/CU

  lin_attn_ctx<<<dim3(B_ * bpb_ctx), dim3(1024), 0, stream>>>(x, wqkv, Ws);
  lin_attn_redg<<<dim3(B_ * 32), dim3(256), 0, stream>>>(Ws, bpb_ctx, wout, G);
  lin_attn_out<<<dim3(B_ * 32), dim3(1024), 0, stream>>>(x, wqkv, G, bout,
                                                         alpha, beta, outp);
}

// Round 11
// 197.064 us; speedup vs baseline: 1.0769x; 1.0142x over previous
//
#include <hip/hip_runtime.h>
#include <math.h>

#define B_ 8
#define C_ 128
#define N_ 16384
#define SCALE_ 0.17677669529663687f
#define EPS_ 1e-5f

#define KV_STRIDE 36    // k/v tiles [128][36] fp32 (ctx kernel)
#define XU_STRIDE 68    // packed f16-pair (uint) tile stride
#define REC_ 4224       // per-block record: 4096 P + 128 S

typedef _Float16 half8 __attribute__((ext_vector_type(8)));
typedef float floatx4 __attribute__((ext_vector_type(4)));

static __device__ inline unsigned short f16bits(float v) {
  _Float16 h = (_Float16)v;
  return __builtin_bit_cast(unsigned short, h);
}

// pack two floats into one hi-pair uint and one lo-pair uint (split-f16)
static __device__ inline void pack2(float a0, float a1,
                                    unsigned int& hp, unsigned int& lp) {
  _Float16 h0 = (_Float16)a0;
  _Float16 h1 = (_Float16)a1;
  float l0f = (a0 - (float)h0) * 2048.0f;
  float l1f = (a1 - (float)h1) * 2048.0f;
  hp = ((unsigned int)__builtin_bit_cast(unsigned short, h1) << 16) |
       (unsigned int)__builtin_bit_cast(unsigned short, h0);
  lp = ((unsigned int)f16bits(l1f) << 16) | (unsigned int)f16bits(l0f);
}

static __device__ inline void split8(const float* p, half8& hi, half8& lo) {
  float4 f0 = *(const float4*)p;
  float4 f1 = *(const float4*)(p + 4);
  float fv[8] = {f0.x, f0.y, f0.z, f0.w, f1.x, f1.y, f1.z, f1.w};
#pragma unroll
  for (int j = 0; j < 8; ++j) {
    _Float16 hj = (_Float16)fv[j];
    hi[j] = hj;
    lo[j] = (_Float16)((fv[j] - (float)hj) * 2048.0f);
  }
}

// ---------------------------------------------------------------------------
// Kernel 1 (16-wave blocks, proven in R8): each wave owns 16 k|v rows;
// P via per-wave MFMA tile-jobs. grid = B_*32, block = 1024.
// ---------------------------------------------------------------------------
__global__ __launch_bounds__(1024, 4) void lin_attn_ctx(
    const float* __restrict__ x, const float* __restrict__ wqkv,
    float* __restrict__ Ws)
{
  __shared__ __align__(16) unsigned int xhiu[32 * XU_STRIDE];
  __shared__ __align__(16) unsigned int xlou[32 * XU_STRIDE];
  __shared__ __align__(16) float ks[128 * KV_STRIDE];
  __shared__ __align__(16) float vs[128 * KV_STRIDE];

  const int t = threadIdx.x;
  const int bpb = gridDim.x / B_;        // 32
  const int b = blockIdx.x / bpb;
  const int blk = blockIdx.x - b * bpb;
  const int nchunks = 512 / bpb;         // 16
  const int pbase = blk * (nchunks << 5);

  const int lane = t & 63;
  const int wave = t >> 6;               // 0..15; waves 0-7: k, 8-15: v
  const int l15 = lane & 15;
  const int quad = lane >> 4;

  half8 ahi[4], alo[4];
#pragma unroll
  for (int s = 0; s < 4; ++s)
    split8(wqkv + (size_t)(128 + (wave << 4) + l15) * C_ + (s << 5) + (quad << 3),
           ahi[s], alo[s]);

  const int hj = wave >> 2;
  const int at = (wave >> 1) & 1;
  const int bt = wave & 1;
  floatx4 pacc1 = (floatx4){0.f, 0.f, 0.f, 0.f};
  floatx4 pacc2 = (floatx4){0.f, 0.f, 0.f, 0.f};
  float sacc[4] = {0.f, 0.f, 0.f, 0.f};

  const float* xb = x + ((size_t)b * C_) * N_;
  const int kp0 = t >> 4;            // 0..63
  const int pq0 = (t & 15) << 1;     // 0,2,..,30

  float2 fa0, fa1;
  {
    const float* p = xb + pbase + pq0;
    fa0 = *(const float2*)(p + (size_t)(2 * kp0) * N_);
    fa1 = *(const float2*)(p + (size_t)(2 * kp0 + 1) * N_);
  }

  for (int c4 = 0; c4 < nchunks; ++c4) {
    __syncthreads();   // A

    half8 eh, el, vh, vl;
    if (c4 > 0) {
      split8(&ks[((hj << 5) + (at << 4) + l15) * KV_STRIDE + (quad << 3)], eh, el);
      split8(&vs[((hj << 5) + (bt << 4) + l15) * KV_STRIDE + (quad << 3)], vh, vl);
    }

    {
      float a0[2] = {fa0.x, fa0.y};
      float a1[2] = {fa1.x, fa1.y};
#pragma unroll
      for (int j = 0; j < 2; ++j) {
        unsigned int hp, lp;
        pack2(a0[j], a1[j], hp, lp);
        xhiu[(pq0 + j) * XU_STRIDE + kp0] = hp;
        xlou[(pq0 + j) * XU_STRIDE + kp0] = lp;
      }
    }

    if (c4 > 0) {
      pacc1 = __builtin_amdgcn_mfma_f32_16x16x32_f16(eh, vh, pacc1, 0, 0, 0);
      pacc2 = __builtin_amdgcn_mfma_f32_16x16x32_f16(eh, vl, pacc2, 0, 0, 0);
      pacc2 = __builtin_amdgcn_mfma_f32_16x16x32_f16(el, vh, pacc2, 0, 0, 0);
    }

    __syncthreads();   // B

    if (c4 + 1 < nchunks) {
      const float* p = xb + pbase + ((c4 + 1) << 5) + pq0;
      fa0 = *(const float2*)(p + (size_t)(2 * kp0) * N_);
      fa1 = *(const float2*)(p + (size_t)(2 * kp0 + 1) * N_);
    }

    floatx4 acc1[2], acc2[2];
#pragma unroll
    for (int c = 0; c < 2; ++c) {
      acc1[c] = (floatx4){0.f, 0.f, 0.f, 0.f};
      acc2[c] = (floatx4){0.f, 0.f, 0.f, 0.f};
    }
    __builtin_amdgcn_s_setprio(1);
#pragma unroll
    for (int s = 0; s < 4; ++s) {
#pragma unroll
      for (int c = 0; c < 2; ++c) {
        int off = ((c << 4) + l15) * XU_STRIDE + (s << 4) + (quad << 2);
        half8 bh = __builtin_bit_cast(half8, *(const uint4*)&xhiu[off]);
        half8 bl = __builtin_bit_cast(half8, *(const uint4*)&xlou[off]);
        acc1[c] = __builtin_amdgcn_mfma_f32_16x16x32_f16(ahi[s], bh, acc1[c], 0, 0, 0);
        acc2[c] = __builtin_amdgcn_mfma_f32_16x16x32_f16(ahi[s], bl, acc2[c], 0, 0, 0);
        acc2[c] = __builtin_amdgcn_mfma_f32_16x16x32_f16(alo[s], bh, acc2[c], 0, 0, 0);
      }
    }
    __builtin_amdgcn_s_setprio(0);

    if (wave < 8) {
#pragma unroll
      for (int c = 0; c < 2; ++c) {
        int px = (c << 4) + l15;
#pragma unroll
        for (int reg = 0; reg < 4; ++reg) {
          float val = acc1[c][reg] + acc2[c][reg] * (1.0f / 2048.0f);
          int row = (wave << 4) + (quad << 2) + reg;
          float e = __expf(val);
          ks[row * KV_STRIDE + px] = e;
          sacc[reg] += e;
        }
      }
    } else {
#pragma unroll
      for (int c = 0; c < 2; ++c) {
        int px = (c << 4) + l15;
#pragma unroll
        for (int reg = 0; reg < 4; ++reg) {
          float val = acc1[c][reg] + acc2[c][reg] * (1.0f / 2048.0f);
          int row = ((wave - 8) << 4) + (quad << 2) + reg;
          vs[row * KV_STRIDE + px] = val;
        }
      }
    }
  }

  __syncthreads();
  {
    half8 eh, el, vh, vl;
    split8(&ks[((hj << 5) + (at << 4) + l15) * KV_STRIDE + (quad << 3)], eh, el);
    split8(&vs[((hj << 5) + (bt << 4) + l15) * KV_STRIDE + (quad << 3)], vh, vl);
    pacc1 = __builtin_amdgcn_mfma_f32_16x16x32_f16(eh, vh, pacc1, 0, 0, 0);
    pacc2 = __builtin_amdgcn_mfma_f32_16x16x32_f16(eh, vl, pacc2, 0, 0, 0);
    pacc2 = __builtin_amdgcn_mfma_f32_16x16x32_f16(el, vh, pacc2, 0, 0, 0);
  }

  {
    float* rec = Ws + (size_t)blockIdx.x * REC_;
#pragma unroll
    for (int reg = 0; reg < 4; ++reg) {
      int dk = (at << 4) + (quad << 2) + reg;
      int dv = (bt << 4) + l15;
      rec[(((hj << 5) + dk) << 5) + dv] =
          pacc1[reg] + pacc2[reg] * (1.0f / 2048.0f);
    }
    if (wave < 8) {
#pragma unroll
      for (int reg = 0; reg < 4; ++reg) {
        float s = sacc[reg];
        s += __shfl_xor(s, 1);
        s += __shfl_xor(s, 2);
        s += __shfl_xor(s, 4);
        s += __shfl_xor(s, 8);
        sacc[reg] = s;
      }
      if (l15 == 0) {
#pragma unroll
        for (int reg = 0; reg < 4; ++reg)
          rec[4096 + (wave << 4) + (quad << 2) + reg] = sacc[reg];
      }
    }
  }
}

// ---------------------------------------------------------------------------
// Fused reduce+gmat (UNCHANGED): grid = B_*32, block = 256
// ---------------------------------------------------------------------------
__global__ void lin_attn_redg(const float* __restrict__ Ws, int slots,
                              const float* __restrict__ wout,
                              float* __restrict__ G)
{
  __shared__ float p2[256];
  __shared__ float cx[128];
  __shared__ float ss[4];

  const int t = threadIdx.x;
  const int b = blockIdx.x >> 5;
  const int seg = blockIdx.x & 31;
  const int R0 = seg << 2;
  const int hs = slots >> 1;

  {
    const int e = t & 127;
    const int half = t >> 7;
    const float* src = Ws + ((size_t)b * slots + (size_t)half * hs) * REC_ +
                       R0 * 32 + e;
    float s = 0.f;
    for (int k = 0; k < hs; ++k) s += src[(size_t)k * REC_];
    p2[half * 128 + e] = s;
  }
  {
    const int row4 = t >> 6;
    const int lane = t & 63;
    float sv = (lane < slots)
             ? Ws[((size_t)b * slots + lane) * REC_ + 4096 + R0 + row4] : 0.f;
    sv += __shfl_xor(sv, 1);
    sv += __shfl_xor(sv, 2);
    sv += __shfl_xor(sv, 4);
    sv += __shfl_xor(sv, 8);
    sv += __shfl_xor(sv, 16);
    sv += __shfl_xor(sv, 32);
    if (lane == 0) ss[row4] = sv;
  }
  __syncthreads();
  if (t < 128) {
    cx[t] = (p2[t] + p2[128 + t]) / (ss[t >> 5] * 16384.f);
  }
  __syncthreads();
  {
    const int o = t >> 1;
    const int pr = t & 1;
#pragma unroll
    for (int p = 0; p < 2; ++p) {
      const int row4 = pr * 2 + p;
      const int grow = R0 + row4;
      const int h = grow >> 5;
      const float* wrow = wout + (size_t)o * 128 + h * 32;
      const float* crow = &cx[row4 * 32];
      float s = 0.f;
#pragma unroll
      for (int q = 0; q < 8; ++q) {
        float4 w4 = *(const float4*)&wrow[q * 4];
        float4 c4 = *(const float4*)&crow[q * 4];
        s += w4.x * c4.x + w4.y * c4.y + w4.z * c4.z + w4.w * c4.w;
      }
      G[(size_t)b * 16384 + (size_t)o * 128 + grow] = s * SCALE_;
    }
  }
}

// ---------------------------------------------------------------------------
// Kernel 2 (REVERTED to round-8/round-6 proven version): 4-wave blocks,
// 2 barriers/chunk, deferred LayerNorm; double-buffered x tile.
// iter i: prefetch(i+1) | qGEMM(i) | softmax(i) | [a] LNfinal(i-1)+store,
//         emit(i), stage(i+1) | [b] yGEMM(i) | yv=y+bias | LNpartials(i).
// grid = B_*64, block = 256.
// ---------------------------------------------------------------------------
__global__ __launch_bounds__(256, 2) void lin_attn_out(
    const float* __restrict__ x, const float* __restrict__ wqkv,
    const float* __restrict__ G, const float* __restrict__ bout,
    const float* __restrict__ alpha, const float* __restrict__ beta,
    float* __restrict__ out)
{
  __shared__ __align__(16) unsigned int xh[2][32 * XU_STRIDE];
  __shared__ __align__(16) unsigned int xl[2][32 * XU_STRIDE];
  __shared__ __align__(16) unsigned int qhiu[32 * XU_STRIDE];
  __shared__ __align__(16) unsigned int qlou[32 * XU_STRIDE];
  __shared__ float red_s[128];
  __shared__ float red_q[128];

  const int t = threadIdx.x;
  const int bpb = gridDim.x / B_;
  const int b = blockIdx.x / bpb;
  const int blk = blockIdx.x - b * bpb;
  const int nchunks = 512 / bpb;
  const int pbase = blk * (nchunks << 5);

  const int lane = t & 63;
  const int wave = t >> 6;
  const int l15 = lane & 15;
  const int quad = lane >> 4;

  half8 qhiA[2][4], qloA[2][4], ghiA[2][4], gloA[2][4];
#pragma unroll
  for (int r = 0; r < 2; ++r) {
#pragma unroll
    for (int s = 0; s < 4; ++s) {
      const int m = (wave << 5) + (r << 4) + l15;
      split8(wqkv + (size_t)m * C_ + (s << 5) + (quad << 3), qhiA[r][s], qloA[r][s]);
      split8(G + (size_t)b * 16384 + (size_t)m * 128 + (s << 5) + (quad << 3),
             ghiA[r][s], gloA[r][s]);
    }
  }

  float bch[8], ach[8], bech[8];
#pragma unroll
  for (int r = 0; r < 2; ++r)
#pragma unroll
    for (int reg = 0; reg < 4; ++reg) {
      int ch = (wave << 5) + (r << 4) + (quad << 2) + reg;
      bch[r * 4 + reg] = bout[ch];
      ach[r * 4 + reg] = alpha[ch];
      bech[r * 4 + reg] = beta[ch];
    }

  const float* xb = x + ((size_t)b * C_) * N_;
  const int kp0 = t >> 3;
  const int pq0 = (t & 7) << 2;
  float4 fa0, fa1, fb0, fb1;

  {
    const float* p = xb + pbase + pq0;
    fa0 = *(const float4*)(p + (size_t)(2 * kp0) * N_);
    fa1 = *(const float4*)(p + (size_t)(2 * kp0 + 1) * N_);
    fb0 = *(const float4*)(p + (size_t)(2 * kp0 + 64) * N_);
    fb1 = *(const float4*)(p + (size_t)(2 * kp0 + 65) * N_);
    float a0[4] = {fa0.x, fa0.y, fa0.z, fa0.w};
    float a1[4] = {fa1.x, fa1.y, fa1.z, fa1.w};
    float c0[4] = {fb0.x, fb0.y, fb0.z, fb0.w};
    float c1[4] = {fb1.x, fb1.y, fb1.z, fb1.w};
#pragma unroll
    for (int j = 0; j < 4; ++j) {
      unsigned int hp, lp;
      pack2(a0[j], a1[j], hp, lp);
      xh[0][(pq0 + j) * XU_STRIDE + kp0] = hp;
      xl[0][(pq0 + j) * XU_STRIDE + kp0] = lp;
      pack2(c0[j], c1[j], hp, lp);
      xh[0][(pq0 + j) * XU_STRIDE + kp0 + 32] = hp;
      xl[0][(pq0 + j) * XU_STRIDE + kp0 + 32] = lp;
    }
  }
  __syncthreads();

  float yv[2][8];

  for (int c4 = 0; c4 < nchunks; ++c4) {
    const int cur = c4 & 1;
    const int nxt = cur ^ 1;

    if (c4 + 1 < nchunks) {
      const float* p = xb + pbase + ((c4 + 1) << 5) + pq0;
      fa0 = *(const float4*)(p + (size_t)(2 * kp0) * N_);
      fa1 = *(const float4*)(p + (size_t)(2 * kp0 + 1) * N_);
      fb0 = *(const float4*)(p + (size_t)(2 * kp0 + 64) * N_);
      fb1 = *(const float4*)(p + (size_t)(2 * kp0 + 65) * N_);
    }

    // ---- q GEMM from xh[cur] ----
    floatx4 a1a[2][2], a2a[2][2];
#pragma unroll
    for (int r = 0; r < 2; ++r)
#pragma unroll
      for (int c = 0; c < 2; ++c) {
        a1a[r][c] = (floatx4){0.f, 0.f, 0.f, 0.f};
        a2a[r][c] = (floatx4){0.f, 0.f, 0.f, 0.f};
      }
    __builtin_amdgcn_s_setprio(1);
#pragma unroll
    for (int s = 0; s < 4; ++s) {
#pragma unroll
      for (int c = 0; c < 2; ++c) {
        int off = ((c << 4) + l15) * XU_STRIDE + (s << 4) + (quad << 2);
        half8 bh = __builtin_bit_cast(half8, *(const uint4*)&xh[cur][off]);
        half8 bl = __builtin_bit_cast(half8, *(const uint4*)&xl[cur][off]);
#pragma unroll
        for (int r = 0; r < 2; ++r) {
          a1a[r][c] = __builtin_amdgcn_mfma_f32_16x16x32_f16(qhiA[r][s], bh, a1a[r][c], 0, 0, 0);
          a2a[r][c] = __builtin_amdgcn_mfma_f32_16x16x32_f16(qhiA[r][s], bl, a2a[r][c], 0, 0, 0);
          a2a[r][c] = __builtin_amdgcn_mfma_f32_16x16x32_f16(qloA[r][s], bh, a2a[r][c], 0, 0, 0);
        }
      }
    }
    __builtin_amdgcn_s_setprio(0);

    // ---- in-register head softmax ----
    float eq[2][8];
#pragma unroll
    for (int c = 0; c < 2; ++c) {
      float qv[8];
#pragma unroll
      for (int r = 0; r < 2; ++r)
#pragma unroll
        for (int reg = 0; reg < 4; ++reg)
          qv[r * 4 + reg] = a1a[r][c][reg] + a2a[r][c][reg] * (1.0f / 2048.0f);
      float mx = fmaxf(fmaxf(fmaxf(qv[0], qv[1]), fmaxf(qv[2], qv[3])),
                       fmaxf(fmaxf(qv[4], qv[5]), fmaxf(qv[6], qv[7])));
      mx = fmaxf(mx, __shfl_xor(mx, 16));
      mx = fmaxf(mx, __shfl_xor(mx, 32));
      float ss = 0.f;
#pragma unroll
      for (int j = 0; j < 8; ++j) { eq[c][j] = __expf(qv[j] - mx); ss += eq[c][j]; }
      ss += __shfl_xor(ss, 16);
      ss += __shfl_xor(ss, 32);
      float inv = 1.0f / ss;
#pragma unroll
      for (int j = 0; j < 8; ++j) eq[c][j] *= inv;
    }
    __syncthreads();   // alpha

    // ---- deferred LN-final + store for PREVIOUS chunk ----
    if (c4 > 0) {
      float* ob = out + ((size_t)b * C_) * N_ + pbase + ((c4 - 1) << 5);
#pragma unroll
      for (int c = 0; c < 2; ++c) {
        int px = (c << 4) + l15;
        float ts = red_s[px] + red_s[32 + px] + red_s[64 + px] + red_s[96 + px];
        float tq = red_q[px] + red_q[32 + px] + red_q[64 + px] + red_q[96 + px];
        float mean = ts * (1.f / 128.f);
        float var = tq * (1.f / 128.f) - mean * mean;
        float rstd = 1.f / sqrtf(var + EPS_);
#pragma unroll
        for (int r = 0; r < 2; ++r)
#pragma unroll
          for (int reg = 0; reg < 4; ++reg) {
            int ch = (wave << 5) + (r << 4) + (quad << 2) + reg;
            ob[(size_t)ch * N_ + px] =
                (yv[c][r * 4 + reg] - mean) * rstd * ach[r * 4 + reg] + bech[r * 4 + reg];
          }
      }
    }

    // ---- emit qhat ----
#pragma unroll
    for (int c = 0; c < 2; ++c) {
      int px = (c << 4) + l15;
#pragma unroll
      for (int r = 0; r < 2; ++r) {
        unsigned int h0, l0, h1, l1;
        pack2(eq[c][r * 4 + 0], eq[c][r * 4 + 1], h0, l0);
        pack2(eq[c][r * 4 + 2], eq[c][r * 4 + 3], h1, l1);
        int kp = (wave << 4) + (r << 3) + (quad << 1);
        uint2 hu; hu.x = h0; hu.y = h1;
        uint2 lu; lu.x = l0; lu.y = l1;
        *(uint2*)&qhiu[px * XU_STRIDE + kp] = hu;
        *(uint2*)&qlou[px * XU_STRIDE + kp] = lu;
      }
    }
    // ---- stage next chunk into xh[nxt] ----
    if (c4 + 1 < nchunks) {
      float a0[4] = {fa0.x, fa0.y, fa0.z, fa0.w};
      float a1[4] = {fa1.x, fa1.y, fa1.z, fa1.w};
      float c0[4] = {fb0.x, fb0.y, fb0.z, fb0.w};
      float c1[4] = {fb1.x, fb1.y, fb1.z, fb1.w};
#pragma unroll
      for (int j = 0; j < 4; ++j) {
        unsigned int hp, lp;
        pack2(a0[j], a1[j], hp, lp);
        xh[nxt][(pq0 + j) * XU_STRIDE + kp0] = hp;
        xl[nxt][(pq0 + j) * XU_STRIDE + kp0] = lp;
        pack2(c0[j], c1[j], hp, lp);
        xh[nxt][(pq0 + j) * XU_STRIDE + kp0 + 32] = hp;
        xl[nxt][(pq0 + j) * XU_STRIDE + kp0 + 32] = lp;
      }
    }
    __syncthreads();   // beta

    // ---- y GEMM: y = G * qhat ----
#pragma unroll
    for (int r = 0; r < 2; ++r)
#pragma unroll
      for (int c = 0; c < 2; ++c) {
        a1a[r][c] = (floatx4){0.f, 0.f, 0.f, 0.f};
        a2a[r][c] = (floatx4){0.f, 0.f, 0.f, 0.f};
      }
    __builtin_amdgcn_s_setprio(1);
#pragma unroll
    for (int s = 0; s < 4; ++s) {
#pragma unroll
      for (int c = 0; c < 2; ++c) {
        int off = ((c << 4) + l15) * XU_STRIDE + (s << 4) + (quad << 2);
        half8 bh = __builtin_bit_cast(half8, *(const uint4*)&qhiu[off]);
        half8 bl = __builtin_bit_cast(half8, *(const uint4*)&qlou[off]);
#pragma unroll
        for (int r = 0; r < 2; ++r) {
          a1a[r][c] = __builtin_amdgcn_mfma_f32_16x16x32_f16(ghiA[r][s], bh, a1a[r][c], 0, 0, 0);
          a2a[r][c] = __builtin_amdgcn_mfma_f32_16x16x32_f16(ghiA[r][s], bl, a2a[r][c], 0, 0, 0);
          a2a[r][c] = __builtin_amdgcn_mfma_f32_16x16x32_f16(gloA[r][s], bh, a2a[r][c], 0, 0, 0);
        }
      }
    }
    __builtin_amdgcn_s_setprio(0);

    // ---- y + bias into yv; LayerNorm partials ----
#pragma unroll
    for (int c = 0; c < 2; ++c) {
      float sm = 0.f, sq = 0.f;
#pragma unroll
      for (int r = 0; r < 2; ++r)
#pragma unroll
        for (int reg = 0; reg < 4; ++reg) {
          float v = a1a[r][c][reg] + a2a[r][c][reg] * (1.0f / 2048.0f) + bch[r * 4 + reg];
          yv[c][r * 4 + reg] = v;
          sm += v;
          sq += v * v;
        }
      sm += __shfl_xor(sm, 16);  sq += __shfl_xor(sq, 16);
      sm += __shfl_xor(sm, 32);  sq += __shfl_xor(sq, 32);
      if (quad == 0) {
        red_s[(wave << 5) + (c << 4) + l15] = sm;
        red_q[(wave << 5) + (c << 4) + l15] = sq;
      }
    }
  }

  // ---- epilogue: LN-final + store for the last chunk ----
  __syncthreads();
  {
    float* ob = out + ((size_t)b * C_) * N_ + pbase + ((nchunks - 1) << 5);
#pragma unroll
    for (int c = 0; c < 2; ++c) {
      int px = (c << 4) + l15;
      float ts = red_s[px] + red_s[32 + px] + red_s[64 + px] + red_s[96 + px];
      float tq = red_q[px] + red_q[32 + px] + red_q[64 + px] + red_q[96 + px];
      float mean = ts * (1.f / 128.f);
      float var = tq * (1.f / 128.f) - mean * mean;
      float rstd = 1.f / sqrtf(var + EPS_);
#pragma unroll
      for (int r = 0; r < 2; ++r)
#pragma unroll
        for (int reg = 0; reg < 4; ++reg) {
          int ch = (wave << 5) + (r << 4) + (quad << 2) + reg;
          ob[(size_t)ch * N_ + px] =
              (yv[c][r * 4 + reg] - mean) * rstd * ach[r * 4 + reg] + bech[r * 4 + reg];
        }
    }
  }
}

extern "C" void kernel_launch(void* const* d_in, const int* in_sizes, int n_in,
                              void* d_out, int out_size, void* d_ws, size_t ws_size,
                              hipStream_t stream) {
  const float* x     = (const float*)d_in[0];
  const float* wqkv  = (const float*)d_in[1];
  const float* wout  = (const float*)d_in[2];
  const float* bout  = (const float*)d_in[3];
  const float* alpha = (const float*)d_in[4];
  const float* beta  = (const float*)d_in[5];
  float* outp = (float*)d_out;

  // workspace layout: G | (reserved) | records
  float* G  = (float*)d_ws;                          // [B][128][128]
  float* Ws = G + (size_t)B_ * 16384 + B_ * 4096 + B_ * 128;

  const int bpb_ctx = 32;   // 256 blocks of 1024 threads = 1 block/CU

  lin_attn_ctx<<<dim3(B_ * bpb_ctx), dim3(1024), 0, stream>>>(x, wqkv, Ws);
  lin_attn_redg<<<dim3(B_ * 32), dim3(256), 0, stream>>>(Ws, bpb_ctx, wout, G);
  lin_attn_out<<<dim3(B_ * 64), dim3(256), 0, stream>>>(x, wqkv, G, bout,
                                                        alpha, beta, outp);
}